// Round 1
// baseline (973.500 us; speedup 1.0000x reference)
//
#include <hip/hip_runtime.h>

#define D 128
#define D2 64   // float2 elems per row
#define D4 32   // float4 elems per row

// ---------------- CSR build ----------------
__global__ void hist_kernel(const int* __restrict__ dst, int* __restrict__ cnt, int E) {
  int e = blockIdx.x * blockDim.x + threadIdx.x;
  if (e < E) atomicAdd(&cnt[dst[e]], 1);
}

#define SCAN_TPB 256
#define SCAN_EPT 8
#define SCAN_CHUNK (SCAN_TPB * SCAN_EPT)  // 2048

__global__ void scan1_kernel(const int* __restrict__ cnt, int* __restrict__ rowptr,
                             int* __restrict__ bsums, int N) {
  __shared__ int lds[SCAN_TPB];
  int tid = threadIdx.x;
  int base = blockIdx.x * SCAN_CHUNK + tid * SCAN_EPT;
  int v[SCAN_EPT];
  int tsum = 0;
#pragma unroll
  for (int j = 0; j < SCAN_EPT; j++) {
    int i = base + j;
    v[j] = (i < N) ? cnt[i] : 0;
    tsum += v[j];
  }
  lds[tid] = tsum;
  __syncthreads();
  for (int off = 1; off < SCAN_TPB; off <<= 1) {
    int t = (tid >= off) ? lds[tid - off] : 0;
    __syncthreads();
    lds[tid] += t;
    __syncthreads();
  }
  int excl = lds[tid] - tsum;
  if (tid == SCAN_TPB - 1) bsums[blockIdx.x] = lds[tid];
  int run = excl;
#pragma unroll
  for (int j = 0; j < SCAN_EPT; j++) {
    int i = base + j;
    if (i < N) rowptr[i] = run;
    run += v[j];
  }
}

__global__ void scan2_kernel(int* bsums, int nb) {
  if (threadIdx.x == 0 && blockIdx.x == 0) {
    int run = 0;
    for (int i = 0; i < nb; i++) { int t = bsums[i]; bsums[i] = run; run += t; }
  }
}

__global__ void scan3_kernel(int* __restrict__ rowptr, const int* __restrict__ bsums,
                             int N, int E) {
  int tid = threadIdx.x;
  int base = blockIdx.x * SCAN_CHUNK + tid * SCAN_EPT;
  int off = bsums[blockIdx.x];
#pragma unroll
  for (int j = 0; j < SCAN_EPT; j++) {
    int i = base + j;
    if (i < N) rowptr[i] += off;
  }
  if (blockIdx.x == 0 && tid == 0) rowptr[N] = E;
}

__global__ void scatter_kernel(const int* __restrict__ src, const int* __restrict__ dst,
                               const int* __restrict__ rowptr, int* __restrict__ cursor,
                               int* __restrict__ csr_src, int E) {
  int e = blockIdx.x * blockDim.x + threadIdx.x;
  if (e < E) {
    int d = dst[e];
    int pos = rowptr[d] + atomicAdd(&cursor[d], 1);
    csr_src[pos] = src[e];
  }
}

// ---------------- mean aggregation (one wave per node) ----------------
__global__ void agg_kernel(const float* __restrict__ h, const int* __restrict__ xmap,
                           const int* __restrict__ rowptr, const int* __restrict__ csr_src,
                           float* __restrict__ mean, int N) {
  int node = (int)((blockIdx.x * (unsigned)blockDim.x + threadIdx.x) >> 6);
  int lane = threadIdx.x & 63;
  if (node >= N) return;
  int beg = rowptr[node], end = rowptr[node + 1];
  float2 acc = make_float2(0.f, 0.f);
  const float2* h2 = (const float2*)h;
  for (int e = beg; e < end; e++) {
    int s = csr_src[e];
    if (xmap) s = xmap[s];
    float2 v = h2[(size_t)s * D2 + lane];
    acc.x += v.x; acc.y += v.y;
  }
  float inv = 1.0f / fmaxf((float)(end - beg), 1.0f);
  float2* m2 = (float2*)mean;
  m2[(size_t)node * D2 + lane] = make_float2(acc.x * inv, acc.y * inv);
}

// ---------------- fused GEMM: out = relu(mean@Wl^T + h@Wr^T + b) ----------------
// K = 256 (first 128 from mean, next 128 from h). Tile 128x128, micro 8x8.
#define TM 128
#define TN 128
#define KC 16
#define LDT (TM + 4)  // padded leading dim (floats)

__global__ __launch_bounds__(256) void gemm_kernel(
    const float* __restrict__ mean, const float* __restrict__ hsrc,
    const int* __restrict__ xmap,
    const float* __restrict__ Wl, const float* __restrict__ Wr,
    const float* __restrict__ bias, float* __restrict__ out, int N) {
  __shared__ float As[KC][LDT];  // [k][row]
  __shared__ float Ws[KC][LDT];  // [k][col]
  int tid = threadIdx.x;
  int tx = tid & 15;   // col group
  int ty = tid >> 4;   // row group
  int row0 = blockIdx.x * TM;

  float acc[8][8];
#pragma unroll
  for (int i = 0; i < 8; i++)
#pragma unroll
    for (int j = 0; j < 8; j++) acc[i][j] = 0.f;

  int kq = (tid & 3) * 4;   // k sub-offset for staging
  int rr = tid >> 2;        // 0..63 staging row/col

  for (int kc = 0; kc < 2 * D; kc += KC) {
    const float* Asrc = (kc < D) ? mean : hsrc;
    const float* Wsrc = (kc < D) ? Wl : Wr;
    int kb = (kc & (D - 1)) + kq;
#pragma unroll
    for (int half = 0; half < 2; half++) {
      int r = rr + half * 64;
      // A tile (transposed into LDS)
      int grow = row0 + r;
      float4 av = make_float4(0.f, 0.f, 0.f, 0.f);
      if (grow < N) {
        int gr = grow;
        if (kc >= D && xmap) gr = xmap[grow];
        av = *(const float4*)(Asrc + (size_t)gr * D + kb);
      }
      As[kq + 0][r] = av.x; As[kq + 1][r] = av.y;
      As[kq + 2][r] = av.z; As[kq + 3][r] = av.w;
      // W tile (transposed into LDS), c == r
      float4 wv = *(const float4*)(Wsrc + (size_t)r * D + kb);
      Ws[kq + 0][r] = wv.x; Ws[kq + 1][r] = wv.y;
      Ws[kq + 2][r] = wv.z; Ws[kq + 3][r] = wv.w;
    }
    __syncthreads();
#pragma unroll
    for (int j = 0; j < KC; j++) {
      float4 a0 = *(const float4*)&As[j][ty * 4];
      float4 a1 = *(const float4*)&As[j][64 + ty * 4];
      float4 w0 = *(const float4*)&Ws[j][tx * 4];
      float4 w1 = *(const float4*)&Ws[j][64 + tx * 4];
      float a[8] = {a0.x, a0.y, a0.z, a0.w, a1.x, a1.y, a1.z, a1.w};
      float w[8] = {w0.x, w0.y, w0.z, w0.w, w1.x, w1.y, w1.z, w1.w};
#pragma unroll
      for (int i = 0; i < 8; i++)
#pragma unroll
        for (int c = 0; c < 8; c++) acc[i][c] = fmaf(a[i], w[c], acc[i][c]);
    }
    __syncthreads();
  }

  // epilogue: + bias, relu, store
  float4 b0 = *(const float4*)(bias + tx * 4);
  float4 b1 = *(const float4*)(bias + 64 + tx * 4);
  float bb[8] = {b0.x, b0.y, b0.z, b0.w, b1.x, b1.y, b1.z, b1.w};
#pragma unroll
  for (int i = 0; i < 8; i++) {
    int r = (i < 4) ? (ty * 4 + i) : (64 + ty * 4 + (i - 4));
    int grow = row0 + r;
    if (grow >= N) continue;
    float4 o0, o1;
    o0.x = fmaxf(acc[i][0] + bb[0], 0.f);
    o0.y = fmaxf(acc[i][1] + bb[1], 0.f);
    o0.z = fmaxf(acc[i][2] + bb[2], 0.f);
    o0.w = fmaxf(acc[i][3] + bb[3], 0.f);
    o1.x = fmaxf(acc[i][4] + bb[4], 0.f);
    o1.y = fmaxf(acc[i][5] + bb[5], 0.f);
    o1.z = fmaxf(acc[i][6] + bb[6], 0.f);
    o1.w = fmaxf(acc[i][7] + bb[7], 0.f);
    *(float4*)(out + (size_t)grow * D + tx * 4) = o0;
    *(float4*)(out + (size_t)grow * D + 64 + tx * 4) = o1;
  }
}

// ---------------- pair dot (32 lanes per pair, float4 coalesced) ----------------
__global__ void pairdot_kernel(const float* __restrict__ h, const int* __restrict__ pairs,
                               float* __restrict__ out, int P) {
  int g = blockIdx.x * blockDim.x + threadIdx.x;
  int p = g >> 5;
  int l = g & 31;
  if (p >= P) return;
  int a = pairs[2 * p], b = pairs[2 * p + 1];
  const float4* u = (const float4*)(h + (size_t)a * D);
  const float4* v = (const float4*)(h + (size_t)b * D);
  float4 x4 = u[l], y4 = v[l];
  float s = x4.x * y4.x + x4.y * y4.y + x4.z * y4.z + x4.w * y4.w;
#pragma unroll
  for (int off = 16; off > 0; off >>= 1) s += __shfl_xor(s, off, 32);
  if (l == 0) out[p] = s;
}

// ---------------- launcher ----------------
extern "C" void kernel_launch(void* const* d_in, const int* in_sizes, int n_in,
                              void* d_out, int out_size, void* d_ws, size_t ws_size,
                              hipStream_t stream) {
  const int*   x     = (const int*)d_in[0];
  const int*   eidx  = (const int*)d_in[1];
  const int*   pairs = (const int*)d_in[2];
  const float* emb   = (const float*)d_in[3];
  const float* Wl0   = (const float*)d_in[4];
  const float* bl0   = (const float*)d_in[5];
  const float* Wr0   = (const float*)d_in[6];
  const float* Wl1   = (const float*)d_in[7];
  const float* bl1   = (const float*)d_in[8];
  const float* Wr1   = (const float*)d_in[9];

  const int N = in_sizes[0];
  const int E = in_sizes[1] / 2;
  const int P = in_sizes[2] / 2;
  const int* src = eidx;        // edge_index[0]
  const int* dst = eidx + E;    // edge_index[1]

  char* ws = (char*)d_ws;
  size_t off = 0;
  float* mean = (float*)(ws + off); off += (size_t)N * D * sizeof(float);
  float* hbuf = (float*)(ws + off); off += (size_t)N * D * sizeof(float);
  int* rowptr = (int*)(ws + off);   off += ((size_t)N + 64) * sizeof(int);
  int* cnt    = (int*)(ws + off);   off += ((size_t)N + 64) * sizeof(int);
  int* cursor = (int*)(ws + off);   off += ((size_t)N + 64) * sizeof(int);
  int* bsums  = (int*)(ws + off);   off += 4096;
  int* csr    = (int*)(ws + off);   off += (size_t)E * sizeof(int);
  (void)ws_size; (void)n_in; (void)out_size;

  hipMemsetAsync(cnt, 0, (size_t)N * sizeof(int), stream);
  hipMemsetAsync(cursor, 0, (size_t)N * sizeof(int), stream);

  int nbE = (E + 255) / 256;
  int nbS = (N + SCAN_CHUNK - 1) / SCAN_CHUNK;
  hist_kernel<<<nbE, 256, 0, stream>>>(dst, cnt, E);
  scan1_kernel<<<nbS, SCAN_TPB, 0, stream>>>(cnt, rowptr, bsums, N);
  scan2_kernel<<<1, 64, 0, stream>>>(bsums, nbS);
  scan3_kernel<<<nbS, SCAN_TPB, 0, stream>>>(rowptr, bsums, N, E);
  scatter_kernel<<<nbE, 256, 0, stream>>>(src, dst, rowptr, cursor, csr, E);

  int nbA = (N + 3) / 4;        // 4 waves (nodes) per 256-thread block
  int nbG = (N + TM - 1) / TM;

  // layer 0: h = emb[x]
  agg_kernel<<<nbA, 256, 0, stream>>>(emb, x, rowptr, csr, mean, N);
  gemm_kernel<<<nbG, 256, 0, stream>>>(mean, emb, x, Wl0, Wr0, bl0, hbuf, N);
  // layer 1: h = hbuf (in-place GEMM is safe: each block writes only rows it read)
  agg_kernel<<<nbA, 256, 0, stream>>>(hbuf, nullptr, rowptr, csr, mean, N);
  gemm_kernel<<<nbG, 256, 0, stream>>>(mean, hbuf, nullptr, Wl1, Wr1, bl1, hbuf, N);

  // link scores
  pairdot_kernel<<<(P * 32 + 255) / 256, 256, 0, stream>>>(hbuf, pairs, (float*)d_out, P);
}

// Round 2
// 716.437 us; speedup vs baseline: 1.3588x; 1.3588x over previous
//
#include <hip/hip_runtime.h>
#include <hip/hip_fp16.h>

#define D 128

__device__ inline float2 h2f(unsigned int u) {
  __half2 h = *(__half2*)&u;
  return __half22float2(h);
}
__device__ inline unsigned int f2h(float a, float b) {
  __half2 h = __floats2half2_rn(a, b);
  return *(unsigned int*)&h;
}

// ---------------- CSR build ----------------
__global__ void hist_kernel(const int* __restrict__ dst, int* __restrict__ cnt, int E) {
  int e = blockIdx.x * blockDim.x + threadIdx.x;
  if (e < E) atomicAdd(&cnt[dst[e]], 1);
}

#define SCAN_TPB 256
#define SCAN_EPT 8
#define SCAN_CHUNK (SCAN_TPB * SCAN_EPT)  // 2048

__global__ void scan1_kernel(const int* __restrict__ cnt, int* __restrict__ rowptr,
                             int* __restrict__ bsums, int N) {
  __shared__ int lds[SCAN_TPB];
  int tid = threadIdx.x;
  int base = blockIdx.x * SCAN_CHUNK + tid * SCAN_EPT;
  int v[SCAN_EPT];
  int tsum = 0;
#pragma unroll
  for (int j = 0; j < SCAN_EPT; j++) {
    int i = base + j;
    v[j] = (i < N) ? cnt[i] : 0;
    tsum += v[j];
  }
  lds[tid] = tsum;
  __syncthreads();
  for (int off = 1; off < SCAN_TPB; off <<= 1) {
    int t = (tid >= off) ? lds[tid - off] : 0;
    __syncthreads();
    lds[tid] += t;
    __syncthreads();
  }
  int excl = lds[tid] - tsum;
  if (tid == SCAN_TPB - 1) bsums[blockIdx.x] = lds[tid];
  int run = excl;
#pragma unroll
  for (int j = 0; j < SCAN_EPT; j++) {
    int i = base + j;
    if (i < N) rowptr[i] = run;
    run += v[j];
  }
}

__global__ void scan2_kernel(int* bsums, int nb) {
  if (threadIdx.x == 0 && blockIdx.x == 0) {
    int run = 0;
    for (int i = 0; i < nb; i++) { int t = bsums[i]; bsums[i] = run; run += t; }
  }
}

__global__ void scan3_kernel(int* __restrict__ rowptr, const int* __restrict__ bsums,
                             int N, int E) {
  int tid = threadIdx.x;
  int base = blockIdx.x * SCAN_CHUNK + tid * SCAN_EPT;
  int off = bsums[blockIdx.x];
#pragma unroll
  for (int j = 0; j < SCAN_EPT; j++) {
    int i = base + j;
    if (i < N) rowptr[i] += off;
  }
  if (blockIdx.x == 0 && tid == 0) rowptr[N] = E;
}

__global__ void scatter_kernel(const int* __restrict__ src, const int* __restrict__ dst,
                               const int* __restrict__ rowptr, int* __restrict__ cursor,
                               int* __restrict__ csr_src, int E) {
  int e = blockIdx.x * blockDim.x + threadIdx.x;
  if (e < E) {
    int d = dst[e];
    int pos = rowptr[d] + atomicAdd(&cursor[d], 1);
    csr_src[pos] = src[e];
  }
}

// ---------------- hx = fp16(emb[x]) (one wave per row, coalesced) ----------------
__global__ void cast_kernel(const float* __restrict__ emb, const int* __restrict__ x,
                            __half* __restrict__ hx, int N) {
  int w = (int)((blockIdx.x * (unsigned)blockDim.x + threadIdx.x) >> 6);
  int lane = threadIdx.x & 63;
  if (w >= N) return;
  int xi = x[w];
  float2 v = ((const float2*)(emb + (size_t)xi * D))[lane];
  ((__half2*)(hx + (size_t)w * D))[lane] = __floats2half2_rn(v.x, v.y);
}

// ---------------- mean aggregation (one wave per node, fp16 gather, x4 unroll) ----
__global__ void agg_kernel(const __half* __restrict__ hh, const int* __restrict__ rowptr,
                           const int* __restrict__ csr, __half* __restrict__ mh, int N) {
  int node = (int)((blockIdx.x * (unsigned)blockDim.x + threadIdx.x) >> 6);
  int lane = threadIdx.x & 63;
  if (node >= N) return;
  int beg = rowptr[node], end = rowptr[node + 1];
  const unsigned int* h1 = (const unsigned int*)hh;  // 2 halves per uint, row stride 64
  float sx = 0.f, sy = 0.f;
  int e = beg;
  for (; e + 4 <= end; e += 4) {
    int s0 = csr[e], s1 = csr[e + 1], s2 = csr[e + 2], s3 = csr[e + 3];
    unsigned int a = h1[(size_t)s0 * 64 + lane];
    unsigned int b = h1[(size_t)s1 * 64 + lane];
    unsigned int c = h1[(size_t)s2 * 64 + lane];
    unsigned int d = h1[(size_t)s3 * 64 + lane];
    float2 fa = h2f(a), fb = h2f(b), fc = h2f(c), fd = h2f(d);
    sx += (fa.x + fb.x) + (fc.x + fd.x);
    sy += (fa.y + fb.y) + (fc.y + fd.y);
  }
  for (; e < end; e++) {
    float2 fa = h2f(h1[(size_t)csr[e] * 64 + lane]);
    sx += fa.x; sy += fa.y;
  }
  float inv = 1.0f / fmaxf((float)(end - beg), 1.0f);
  ((__half2*)mh)[(size_t)node * 64 + lane] = __floats2half2_rn(sx * inv, sy * inv);
}

// ---------------- fused GEMM: out = fp16(relu(mean@Wl^T + h@Wr^T + b)) ------------
// K = 256 (first 128 from mean_h, next 128 from hsrc). Tile 128x128, micro 8x8.
// In-place safe: each block reads only its own 128 rows of A (k-loop), then writes
// the same rows in the epilogue after the final __syncthreads.
#define TM 128
#define KC 16
#define LDT (TM + 4)

__global__ __launch_bounds__(256) void gemm_kernel(
    const __half* __restrict__ mh, const __half* __restrict__ hsrc,
    const float* __restrict__ Wl, const float* __restrict__ Wr,
    const float* __restrict__ bias, __half* __restrict__ out, int N) {
  __shared__ float As[KC][LDT];  // [k][row]
  __shared__ float Ws[KC][LDT];  // [k][col]
  int tid = threadIdx.x;
  int tx = tid & 15;
  int ty = tid >> 4;
  int row0 = blockIdx.x * TM;

  float acc[8][8];
#pragma unroll
  for (int i = 0; i < 8; i++)
#pragma unroll
    for (int j = 0; j < 8; j++) acc[i][j] = 0.f;

  int kq = (tid & 3) * 4;
  int rr = tid >> 2;

  for (int kc = 0; kc < 2 * D; kc += KC) {
    const __half* Asrc = (kc < D) ? mh : hsrc;
    const float* Wsrc = (kc < D) ? Wl : Wr;
    int kb = (kc & (D - 1)) + kq;
#pragma unroll
    for (int half = 0; half < 2; half++) {
      int r = rr + half * 64;
      int grow = row0 + r;
      uint2 av = make_uint2(0u, 0u);
      if (grow < N) av = *(const uint2*)(Asrc + (size_t)grow * D + kb);
      float2 f0 = h2f(av.x), f1 = h2f(av.y);
      As[kq + 0][r] = f0.x; As[kq + 1][r] = f0.y;
      As[kq + 2][r] = f1.x; As[kq + 3][r] = f1.y;
      float4 wv = *(const float4*)(Wsrc + (size_t)r * D + kb);
      Ws[kq + 0][r] = wv.x; Ws[kq + 1][r] = wv.y;
      Ws[kq + 2][r] = wv.z; Ws[kq + 3][r] = wv.w;
    }
    __syncthreads();
#pragma unroll
    for (int j = 0; j < KC; j++) {
      float4 a0 = *(const float4*)&As[j][ty * 4];
      float4 a1 = *(const float4*)&As[j][64 + ty * 4];
      float4 w0 = *(const float4*)&Ws[j][tx * 4];
      float4 w1 = *(const float4*)&Ws[j][64 + tx * 4];
      float a[8] = {a0.x, a0.y, a0.z, a0.w, a1.x, a1.y, a1.z, a1.w};
      float w[8] = {w0.x, w0.y, w0.z, w0.w, w1.x, w1.y, w1.z, w1.w};
#pragma unroll
      for (int i = 0; i < 8; i++)
#pragma unroll
        for (int c = 0; c < 8; c++) acc[i][c] = fmaf(a[i], w[c], acc[i][c]);
    }
    __syncthreads();
  }

  float4 b0 = *(const float4*)(bias + tx * 4);
  float4 b1 = *(const float4*)(bias + 64 + tx * 4);
  float bb[8] = {b0.x, b0.y, b0.z, b0.w, b1.x, b1.y, b1.z, b1.w};
#pragma unroll
  for (int i = 0; i < 8; i++) {
    int r = (i < 4) ? (ty * 4 + i) : (64 + ty * 4 + (i - 4));
    int grow = row0 + r;
    if (grow >= N) continue;
    float r0 = fmaxf(acc[i][0] + bb[0], 0.f);
    float r1 = fmaxf(acc[i][1] + bb[1], 0.f);
    float r2 = fmaxf(acc[i][2] + bb[2], 0.f);
    float r3 = fmaxf(acc[i][3] + bb[3], 0.f);
    float r4 = fmaxf(acc[i][4] + bb[4], 0.f);
    float r5 = fmaxf(acc[i][5] + bb[5], 0.f);
    float r6 = fmaxf(acc[i][6] + bb[6], 0.f);
    float r7 = fmaxf(acc[i][7] + bb[7], 0.f);
    uint2 lo = make_uint2(f2h(r0, r1), f2h(r2, r3));
    uint2 hi = make_uint2(f2h(r4, r5), f2h(r6, r7));
    *(uint2*)(out + (size_t)grow * D + tx * 4) = lo;
    *(uint2*)(out + (size_t)grow * D + 64 + tx * 4) = hi;
  }
}

// ---------------- pair dot (32 lanes per pair, fp16 rows) ----------------
__global__ void pairdot_kernel(const __half* __restrict__ h, const int* __restrict__ pairs,
                               float* __restrict__ out, int P) {
  int g = blockIdx.x * blockDim.x + threadIdx.x;
  int p = g >> 5;
  int l = g & 31;
  if (p >= P) return;
  int a = pairs[2 * p], b = pairs[2 * p + 1];
  const uint2* u = (const uint2*)(h + (size_t)a * D);
  const uint2* v = (const uint2*)(h + (size_t)b * D);
  uint2 ua = u[l], vb = v[l];
  float2 x0 = h2f(ua.x), x1 = h2f(ua.y), y0 = h2f(vb.x), y1 = h2f(vb.y);
  float s = x0.x * y0.x + x0.y * y0.y + x1.x * y1.x + x1.y * y1.y;
#pragma unroll
  for (int off = 16; off > 0; off >>= 1) s += __shfl_xor(s, off, 32);
  if (l == 0) out[p] = s;
}

// ---------------- launcher ----------------
extern "C" void kernel_launch(void* const* d_in, const int* in_sizes, int n_in,
                              void* d_out, int out_size, void* d_ws, size_t ws_size,
                              hipStream_t stream) {
  const int*   x     = (const int*)d_in[0];
  const int*   eidx  = (const int*)d_in[1];
  const int*   pairs = (const int*)d_in[2];
  const float* emb   = (const float*)d_in[3];
  const float* Wl0   = (const float*)d_in[4];
  const float* bl0   = (const float*)d_in[5];
  const float* Wr0   = (const float*)d_in[6];
  const float* Wl1   = (const float*)d_in[7];
  const float* bl1   = (const float*)d_in[8];
  const float* Wr1   = (const float*)d_in[9];

  const int N = in_sizes[0];
  const int E = in_sizes[1] / 2;
  const int P = in_sizes[2] / 2;
  const int* src = eidx;
  const int* dst = eidx + E;

  char* ws = (char*)d_ws;
  size_t off = 0;
  __half* hx  = (__half*)(ws + off); off += (size_t)N * D * sizeof(__half);  // hx -> h1 -> h2
  __half* mh  = (__half*)(ws + off); off += (size_t)N * D * sizeof(__half);  // mean
  int* rowptr = (int*)(ws + off);    off += ((size_t)N + 64) * sizeof(int);
  int* cnt    = (int*)(ws + off);    off += ((size_t)N + 64) * sizeof(int);
  int* cursor = (int*)(ws + off);    off += ((size_t)N + 64) * sizeof(int);
  int* bsums  = (int*)(ws + off);    off += 4096;
  int* csr    = (int*)(ws + off);    off += (size_t)E * sizeof(int);
  (void)ws_size; (void)n_in; (void)out_size;

  hipMemsetAsync(cnt, 0, (size_t)N * sizeof(int), stream);
  hipMemsetAsync(cursor, 0, (size_t)N * sizeof(int), stream);

  int nbE = (E + 255) / 256;
  int nbS = (N + SCAN_CHUNK - 1) / SCAN_CHUNK;
  hist_kernel<<<nbE, 256, 0, stream>>>(dst, cnt, E);
  scan1_kernel<<<nbS, SCAN_TPB, 0, stream>>>(cnt, rowptr, bsums, N);
  scan2_kernel<<<1, 64, 0, stream>>>(bsums, nbS);
  scan3_kernel<<<nbS, SCAN_TPB, 0, stream>>>(rowptr, bsums, N, E);
  scatter_kernel<<<nbE, 256, 0, stream>>>(src, dst, rowptr, cursor, csr, E);

  int nbA = (N + 3) / 4;         // 4 waves (nodes/rows) per 256-thread block
  int nbG = (N + TM - 1) / TM;

  cast_kernel<<<nbA, 256, 0, stream>>>(emb, x, hx, N);

  // layer 0
  agg_kernel<<<nbA, 256, 0, stream>>>(hx, rowptr, csr, mh, N);
  gemm_kernel<<<nbG, 256, 0, stream>>>(mh, hx, Wl0, Wr0, bl0, hx, N);  // hx := h1
  // layer 1
  agg_kernel<<<nbA, 256, 0, stream>>>(hx, rowptr, csr, mh, N);
  gemm_kernel<<<nbG, 256, 0, stream>>>(mh, hx, Wl1, Wr1, bl1, hx, N);  // hx := h2

  pairdot_kernel<<<(P * 32 + 255) / 256, 256, 0, stream>>>(hx, pairs, (float*)d_out, P);
}

// Round 3
// 555.517 us; speedup vs baseline: 1.7524x; 1.2897x over previous
//
#include <hip/hip_runtime.h>
#include <hip/hip_fp16.h>

#define D 128

typedef _Float16 half8 __attribute__((ext_vector_type(8)));
typedef float floatx16 __attribute__((ext_vector_type(16)));

__device__ inline float2 h2f(unsigned int u) {
  __half2 h = *(__half2*)&u;
  return __half22float2(h);
}

// ---------------- CSR build ----------------
__global__ void hist_kernel(const int* __restrict__ dst, int* __restrict__ cnt, int E) {
  int e = blockIdx.x * blockDim.x + threadIdx.x;
  if (e < E) atomicAdd(&cnt[dst[e]], 1);
}

#define SCAN_TPB 256
#define SCAN_EPT 8
#define SCAN_CHUNK (SCAN_TPB * SCAN_EPT)  // 2048

__global__ void scan1_kernel(const int* __restrict__ cnt, int* __restrict__ rowptr,
                             int* __restrict__ bsums, int N) {
  __shared__ int lds[SCAN_TPB];
  int tid = threadIdx.x;
  int base = blockIdx.x * SCAN_CHUNK + tid * SCAN_EPT;
  int v[SCAN_EPT];
  int tsum = 0;
#pragma unroll
  for (int j = 0; j < SCAN_EPT; j++) {
    int i = base + j;
    v[j] = (i < N) ? cnt[i] : 0;
    tsum += v[j];
  }
  lds[tid] = tsum;
  __syncthreads();
  for (int off = 1; off < SCAN_TPB; off <<= 1) {
    int t = (tid >= off) ? lds[tid - off] : 0;
    __syncthreads();
    lds[tid] += t;
    __syncthreads();
  }
  int excl = lds[tid] - tsum;
  if (tid == SCAN_TPB - 1) bsums[blockIdx.x] = lds[tid];
  int run = excl;
#pragma unroll
  for (int j = 0; j < SCAN_EPT; j++) {
    int i = base + j;
    if (i < N) rowptr[i] = run;
    run += v[j];
  }
}

__global__ void scan2_kernel(int* bsums, int nb) {
  if (threadIdx.x == 0 && blockIdx.x == 0) {
    int run = 0;
    for (int i = 0; i < nb; i++) { int t = bsums[i]; bsums[i] = run; run += t; }
  }
}

__global__ void scan3_kernel(int* __restrict__ rowptr, const int* __restrict__ bsums,
                             int N, int E) {
  int tid = threadIdx.x;
  int base = blockIdx.x * SCAN_CHUNK + tid * SCAN_EPT;
  int off = bsums[blockIdx.x];
#pragma unroll
  for (int j = 0; j < SCAN_EPT; j++) {
    int i = base + j;
    if (i < N) rowptr[i] += off;
  }
  if (blockIdx.x == 0 && tid == 0) rowptr[N] = E;
}

__global__ void scatter_kernel(const int* __restrict__ src, const int* __restrict__ dst,
                               const int* __restrict__ rowptr, int* __restrict__ cursor,
                               int* __restrict__ csr_src, int E) {
  int e = blockIdx.x * blockDim.x + threadIdx.x;
  if (e < E) {
    int d = dst[e];
    int pos = rowptr[d] + atomicAdd(&cursor[d], 1);
    csr_src[pos] = src[e];
  }
}

// ---------------- hx = fp16(emb[x]) ----------------
__global__ void cast_kernel(const float* __restrict__ emb, const int* __restrict__ x,
                            __half* __restrict__ hx, int N) {
  int w = (int)((blockIdx.x * (unsigned)blockDim.x + threadIdx.x) >> 6);
  int lane = threadIdx.x & 63;
  if (w >= N) return;
  int xi = x[w];
  float2 v = ((const float2*)(emb + (size_t)xi * D))[lane];
  ((__half2*)(hx + (size_t)w * D))[lane] = __floats2half2_rn(v.x, v.y);
}

// ---------------- mean aggregation (one wave per node, fp16 gather, x4 unroll) ----
__global__ void agg_kernel(const __half* __restrict__ hh, const int* __restrict__ rowptr,
                           const int* __restrict__ csr, __half* __restrict__ mh, int N) {
  int node = (int)((blockIdx.x * (unsigned)blockDim.x + threadIdx.x) >> 6);
  int lane = threadIdx.x & 63;
  if (node >= N) return;
  int beg = rowptr[node], end = rowptr[node + 1];
  const unsigned int* h1 = (const unsigned int*)hh;
  float sx = 0.f, sy = 0.f;
  int e = beg;
  for (; e + 4 <= end; e += 4) {
    int s0 = csr[e], s1 = csr[e + 1], s2 = csr[e + 2], s3 = csr[e + 3];
    unsigned int a = h1[(size_t)s0 * 64 + lane];
    unsigned int b = h1[(size_t)s1 * 64 + lane];
    unsigned int c = h1[(size_t)s2 * 64 + lane];
    unsigned int d = h1[(size_t)s3 * 64 + lane];
    float2 fa = h2f(a), fb = h2f(b), fc = h2f(c), fd = h2f(d);
    sx += (fa.x + fb.x) + (fc.x + fd.x);
    sy += (fa.y + fb.y) + (fc.y + fd.y);
  }
  for (; e < end; e++) {
    float2 fa = h2f(h1[(size_t)csr[e] * 64 + lane]);
    sx += fa.x; sy += fa.y;
  }
  float inv = 1.0f / fmaxf((float)(end - beg), 1.0f);
  ((__half2*)mh)[(size_t)node * 64 + lane] = __floats2half2_rn(sx * inv, sy * inv);
}

// ---------------- pack W into B-fragment order ----------------
// gWsw[(t*16+k0)*64 + lane] (uint4 = 8 halves) = B[k = k0*16 + (lane>>5)*8 + j][n = t*32 + (lane&31)]
// where B[k][n] = k<128 ? Wl[n][k] : Wr[n][k-128]   (out = A @ B, A = [mean|h])
__global__ void packW_kernel(const float* __restrict__ Wl, const float* __restrict__ Wr,
                             uint4* __restrict__ gWsw) {
  int g = blockIdx.x * blockDim.x + threadIdx.x;
  if (g >= 4096) return;
  int lane = g & 63;
  int k0 = (g >> 6) & 15;
  int t = g >> 10;
  int n = t * 32 + (lane & 31);
  int kk = k0 * 16 + (lane >> 5) * 8;
  const float* srcp = (kk < D) ? (Wl + (size_t)n * D + kk) : (Wr + (size_t)n * D + (kk - D));
  float4 f0 = *(const float4*)(srcp);
  float4 f1 = *(const float4*)(srcp + 4);
  __half h[8];
  h[0] = __float2half_rn(f0.x); h[1] = __float2half_rn(f0.y);
  h[2] = __float2half_rn(f0.z); h[3] = __float2half_rn(f0.w);
  h[4] = __float2half_rn(f1.x); h[5] = __float2half_rn(f1.y);
  h[6] = __float2half_rn(f1.z); h[7] = __float2half_rn(f1.w);
  gWsw[g] = *(uint4*)h;
}

// ---------------- MFMA GEMM: out = fp16(relu([mean|h] @ B + bias)) ----------------
// M-tile 128 (4 waves x 32 rows), N = 128 (4 acc tiles of 32), K = 256 (16 mfma steps).
// Wsw preloaded to LDS (64 KB, conflict-free b128 frag reads). Epilogue reuses LDS.
// In-place safe: block reads only its own 128 rows before writing them.
#define OS_PITCH 136  // halves; 272 B rows keep 16B alignment, break bank aliasing

__global__ __launch_bounds__(256) void mfma_gemm_kernel(
    const __half* __restrict__ mh, const __half* __restrict__ hsrc,
    const uint4* __restrict__ gWsw, const float* __restrict__ bias,
    __half* __restrict__ out, int N) {
  __shared__ uint4 lds[4096];  // 64 KB
  int tid = threadIdx.x;
  int wave = tid >> 6, lane = tid & 63;
  int row0 = blockIdx.x * 128;

#pragma unroll
  for (int i = 0; i < 16; i++) lds[i * 256 + tid] = gWsw[i * 256 + tid];
  __syncthreads();

  int mrow = row0 + wave * 32 + (lane & 31);
  int koff = (lane >> 5) * 8;
  bool valid = mrow < N;
  const __half* mrp = mh + (size_t)mrow * D + koff;
  const __half* hrp = hsrc + (size_t)mrow * D + koff;

  floatx16 acc[4];
#pragma unroll
  for (int t = 0; t < 4; t++)
#pragma unroll
    for (int i = 0; i < 16; i++) acc[t][i] = 0.f;

  uint4 areg[8];
  // K half 1: mean
#pragma unroll
  for (int k0 = 0; k0 < 8; k0++) {
    areg[k0] = valid ? *(const uint4*)(mrp + k0 * 16) : make_uint4(0u, 0u, 0u, 0u);
  }
#pragma unroll
  for (int k0 = 0; k0 < 8; k0++) {
    half8 af = *(half8*)&areg[k0];
#pragma unroll
    for (int t = 0; t < 4; t++) {
      half8 bf = *(half8*)&lds[(t * 16 + k0) * 64 + lane];
      acc[t] = __builtin_amdgcn_mfma_f32_32x32x16_f16(af, bf, acc[t], 0, 0, 0);
    }
  }
  // K half 2: h
#pragma unroll
  for (int k0 = 0; k0 < 8; k0++) {
    areg[k0] = valid ? *(const uint4*)(hrp + k0 * 16) : make_uint4(0u, 0u, 0u, 0u);
  }
#pragma unroll
  for (int k0 = 8; k0 < 16; k0++) {
    half8 af = *(half8*)&areg[k0 - 8];
#pragma unroll
    for (int t = 0; t < 4; t++) {
      half8 bf = *(half8*)&lds[(t * 16 + k0) * 64 + lane];
      acc[t] = __builtin_amdgcn_mfma_f32_32x32x16_f16(af, bf, acc[t], 0, 0, 0);
    }
  }

  __syncthreads();  // all waves done reading Wsw; reuse LDS for output staging
  __half* Os = (__half*)lds;
  int col = lane & 31;
  int rsub = 4 * (lane >> 5);
#pragma unroll
  for (int t = 0; t < 4; t++) {
    float bv = bias[t * 32 + col];
#pragma unroll
    for (int r = 0; r < 16; r++) {
      int row = (r & 3) + 8 * (r >> 2) + rsub;  // 0..31 within wave tile
      float v = fmaxf(acc[t][r] + bv, 0.f);
      Os[(size_t)(wave * 32 + row) * OS_PITCH + t * 32 + col] = __float2half_rn(v);
    }
  }
  __syncthreads();
  // coalesced store: 128 rows x 16 uint4
#pragma unroll
  for (int i = 0; i < 8; i++) {
    int idx = i * 256 + tid;
    int row = idx >> 4;
    int c16 = idx & 15;
    int grow = row0 + row;
    if (grow < N) {
      uint4 v = *(uint4*)(Os + (size_t)row * OS_PITCH + c16 * 8);
      *(uint4*)(out + (size_t)grow * D + c16 * 8) = v;
    }
  }
}

// ---------------- pair dot (32 lanes per pair, fp16 rows) ----------------
__global__ void pairdot_kernel(const __half* __restrict__ h, const int* __restrict__ pairs,
                               float* __restrict__ out, int P) {
  int g = blockIdx.x * blockDim.x + threadIdx.x;
  int p = g >> 5;
  int l = g & 31;
  if (p >= P) return;
  int a = pairs[2 * p], b = pairs[2 * p + 1];
  const uint2* u = (const uint2*)(h + (size_t)a * D);
  const uint2* v = (const uint2*)(h + (size_t)b * D);
  uint2 ua = u[l], vb = v[l];
  float2 x0 = h2f(ua.x), x1 = h2f(ua.y), y0 = h2f(vb.x), y1 = h2f(vb.y);
  float s = x0.x * y0.x + x0.y * y0.y + x1.x * y1.x + x1.y * y1.y;
#pragma unroll
  for (int off = 16; off > 0; off >>= 1) s += __shfl_xor(s, off, 32);
  if (l == 0) out[p] = s;
}

// ---------------- launcher ----------------
extern "C" void kernel_launch(void* const* d_in, const int* in_sizes, int n_in,
                              void* d_out, int out_size, void* d_ws, size_t ws_size,
                              hipStream_t stream) {
  const int*   x     = (const int*)d_in[0];
  const int*   eidx  = (const int*)d_in[1];
  const int*   pairs = (const int*)d_in[2];
  const float* emb   = (const float*)d_in[3];
  const float* Wl0   = (const float*)d_in[4];
  const float* bl0   = (const float*)d_in[5];
  const float* Wr0   = (const float*)d_in[6];
  const float* Wl1   = (const float*)d_in[7];
  const float* bl1   = (const float*)d_in[8];
  const float* Wr1   = (const float*)d_in[9];

  const int N = in_sizes[0];
  const int E = in_sizes[1] / 2;
  const int P = in_sizes[2] / 2;
  const int* src = eidx;
  const int* dst = eidx + E;

  char* ws = (char*)d_ws;
  size_t off = 0;
  __half* hx  = (__half*)(ws + off); off += (size_t)N * D * sizeof(__half);  // hx -> h1 -> h2
  __half* mh  = (__half*)(ws + off); off += (size_t)N * D * sizeof(__half);  // mean
  int* rowptr = (int*)(ws + off);    off += ((size_t)N + 64) * sizeof(int);
  int* cnt    = (int*)(ws + off);    off += ((size_t)N + 64) * sizeof(int);
  int* cursor = (int*)(ws + off);    off += ((size_t)N + 64) * sizeof(int);
  int* bsums  = (int*)(ws + off);    off += 4096;
  uint4* gW0  = (uint4*)(ws + off);  off += 65536;
  uint4* gW1  = (uint4*)(ws + off);  off += 65536;
  int* csr    = (int*)(ws + off);    off += (size_t)E * sizeof(int);
  (void)ws_size; (void)n_in; (void)out_size;

  hipMemsetAsync(cnt, 0, (size_t)N * sizeof(int), stream);
  hipMemsetAsync(cursor, 0, (size_t)N * sizeof(int), stream);

  int nbE = (E + 255) / 256;
  int nbS = (N + SCAN_CHUNK - 1) / SCAN_CHUNK;
  hist_kernel<<<nbE, 256, 0, stream>>>(dst, cnt, E);
  scan1_kernel<<<nbS, SCAN_TPB, 0, stream>>>(cnt, rowptr, bsums, N);
  scan2_kernel<<<1, 64, 0, stream>>>(bsums, nbS);
  scan3_kernel<<<nbS, SCAN_TPB, 0, stream>>>(rowptr, bsums, N, E);
  scatter_kernel<<<nbE, 256, 0, stream>>>(src, dst, rowptr, cursor, csr, E);

  packW_kernel<<<16, 256, 0, stream>>>(Wl0, Wr0, gW0);
  packW_kernel<<<16, 256, 0, stream>>>(Wl1, Wr1, gW1);

  int nbA = (N + 3) / 4;
  int nbG = (N + 127) / 128;

  cast_kernel<<<nbA, 256, 0, stream>>>(emb, x, hx, N);

  // layer 0
  agg_kernel<<<nbA, 256, 0, stream>>>(hx, rowptr, csr, mh, N);
  mfma_gemm_kernel<<<nbG, 256, 0, stream>>>(mh, hx, gW0, bl0, hx, N);  // hx := h1
  // layer 1
  agg_kernel<<<nbA, 256, 0, stream>>>(hx, rowptr, csr, mh, N);
  mfma_gemm_kernel<<<nbG, 256, 0, stream>>>(mh, hx, gW1, bl1, hx, N);  // hx := h2

  pairdot_kernel<<<(P * 32 + 255) / 256, 256, 0, stream>>>(hx, pairs, (float*)d_out, P);
}

// Round 4
// 513.093 us; speedup vs baseline: 1.8973x; 1.0827x over previous
//
#include <hip/hip_runtime.h>
#include <hip/hip_fp16.h>

#define D 128

typedef _Float16 half8 __attribute__((ext_vector_type(8)));
typedef float floatx16 __attribute__((ext_vector_type(16)));

__device__ inline float2 h2f(unsigned int u) {
  __half2 h = *(__half2*)&u;
  return __half22float2(h);
}

// ---------------- CSR build ----------------
__global__ void hist_kernel(const int* __restrict__ dst, int* __restrict__ cnt, int E) {
  int e = blockIdx.x * blockDim.x + threadIdx.x;
  if (e < E) atomicAdd(&cnt[dst[e]], 1);
}

#define SCAN_TPB 256
#define SCAN_EPT 8
#define SCAN_CHUNK (SCAN_TPB * SCAN_EPT)  // 2048

__global__ void scan1_kernel(const int* __restrict__ cnt, int* __restrict__ rowptr,
                             int* __restrict__ bsums, int N) {
  __shared__ int lds[SCAN_TPB];
  int tid = threadIdx.x;
  int base = blockIdx.x * SCAN_CHUNK + tid * SCAN_EPT;
  int v[SCAN_EPT];
  int tsum = 0;
#pragma unroll
  for (int j = 0; j < SCAN_EPT; j++) {
    int i = base + j;
    v[j] = (i < N) ? cnt[i] : 0;
    tsum += v[j];
  }
  lds[tid] = tsum;
  __syncthreads();
  for (int off = 1; off < SCAN_TPB; off <<= 1) {
    int t = (tid >= off) ? lds[tid - off] : 0;
    __syncthreads();
    lds[tid] += t;
    __syncthreads();
  }
  int excl = lds[tid] - tsum;
  if (tid == SCAN_TPB - 1) bsums[blockIdx.x] = lds[tid];
  int run = excl;
#pragma unroll
  for (int j = 0; j < SCAN_EPT; j++) {
    int i = base + j;
    if (i < N) rowptr[i] = run;
    run += v[j];
  }
}

__global__ void scan2_kernel(int* bsums, int nb) {
  if (threadIdx.x == 0 && blockIdx.x == 0) {
    int run = 0;
    for (int i = 0; i < nb; i++) { int t = bsums[i]; bsums[i] = run; run += t; }
  }
}

__global__ void scan3_kernel(int* __restrict__ rowptr, const int* __restrict__ bsums,
                             int N, int E) {
  int tid = threadIdx.x;
  int base = blockIdx.x * SCAN_CHUNK + tid * SCAN_EPT;
  int off = bsums[blockIdx.x];
#pragma unroll
  for (int j = 0; j < SCAN_EPT; j++) {
    int i = base + j;
    if (i < N) rowptr[i] += off;
  }
  if (blockIdx.x == 0 && tid == 0) rowptr[N] = E;
}

__global__ void scatter_kernel(const int* __restrict__ src, const int* __restrict__ dst,
                               const int* __restrict__ rowptr, int* __restrict__ cursor,
                               int* __restrict__ csr_src, int E) {
  int e = blockIdx.x * blockDim.x + threadIdx.x;
  if (e < E) {
    int d = dst[e];
    int pos = rowptr[d] + atomicAdd(&cursor[d], 1);
    csr_src[pos] = src[e];
  }
}

// ---------------- hx = fp16(emb[x]) ----------------
__global__ void cast_kernel(const float* __restrict__ emb, const int* __restrict__ x,
                            __half* __restrict__ hx, int N) {
  int w = (int)((blockIdx.x * (unsigned)blockDim.x + threadIdx.x) >> 6);
  int lane = threadIdx.x & 63;
  if (w >= N) return;
  int xi = x[w];
  float2 v = ((const float2*)(emb + (size_t)xi * D))[lane];
  ((__half2*)(hx + (size_t)w * D))[lane] = __floats2half2_rn(v.x, v.y);
}

// ---------------- mean aggregation (one wave per node, 8-deep gather MLP) --------
__global__ void agg_kernel(const __half* __restrict__ hh, const int* __restrict__ rowptr,
                           const int* __restrict__ csr, __half* __restrict__ mh, int N) {
  int node = (int)((blockIdx.x * (unsigned)blockDim.x + threadIdx.x) >> 6);
  int lane = threadIdx.x & 63;
  if (node >= N) return;
  int beg = rowptr[node], end = rowptr[node + 1];
  const unsigned int* h1 = (const unsigned int*)hh;
  float sx = 0.f, sy = 0.f;
  int e = beg;
  for (; e + 8 <= end; e += 8) {
    int s[8];
#pragma unroll
    for (int j = 0; j < 8; j++) s[j] = csr[e + j];
    unsigned int r[8];
#pragma unroll
    for (int j = 0; j < 8; j++) r[j] = h1[(size_t)s[j] * 64 + lane];
#pragma unroll
    for (int j = 0; j < 8; j++) {
      float2 f = h2f(r[j]);
      sx += f.x; sy += f.y;
    }
  }
  for (; e + 2 <= end; e += 2) {
    int s0 = csr[e], s1 = csr[e + 1];
    unsigned int a = h1[(size_t)s0 * 64 + lane];
    unsigned int b = h1[(size_t)s1 * 64 + lane];
    float2 fa = h2f(a), fb = h2f(b);
    sx += fa.x + fb.x; sy += fa.y + fb.y;
  }
  if (e < end) {
    float2 fa = h2f(h1[(size_t)csr[e] * 64 + lane]);
    sx += fa.x; sy += fa.y;
  }
  float inv = 1.0f / fmaxf((float)(end - beg), 1.0f);
  ((__half2*)mh)[(size_t)node * 64 + lane] = __floats2half2_rn(sx * inv, sy * inv);
}

// ---------------- pack W into B-fragment order ----------------
__global__ void packW_kernel(const float* __restrict__ Wl, const float* __restrict__ Wr,
                             uint4* __restrict__ gWsw) {
  int g = blockIdx.x * blockDim.x + threadIdx.x;
  if (g >= 4096) return;
  int lane = g & 63;
  int k0 = (g >> 6) & 15;
  int t = g >> 10;
  int n = t * 32 + (lane & 31);
  int kk = k0 * 16 + (lane >> 5) * 8;
  const float* srcp = (kk < D) ? (Wl + (size_t)n * D + kk) : (Wr + (size_t)n * D + (kk - D));
  float4 f0 = *(const float4*)(srcp);
  float4 f1 = *(const float4*)(srcp + 4);
  __half h[8];
  h[0] = __float2half_rn(f0.x); h[1] = __float2half_rn(f0.y);
  h[2] = __float2half_rn(f0.z); h[3] = __float2half_rn(f0.w);
  h[4] = __float2half_rn(f1.x); h[5] = __float2half_rn(f1.y);
  h[6] = __float2half_rn(f1.z); h[7] = __float2half_rn(f1.w);
  gWsw[g] = *(uint4*)h;
}

// ---------------- MFMA GEMM: out = fp16(relu([mean|h] @ B + bias)) ----------------
#define OS_PITCH 136

__global__ __launch_bounds__(256) void mfma_gemm_kernel(
    const __half* __restrict__ mh, const __half* __restrict__ hsrc,
    const uint4* __restrict__ gWsw, const float* __restrict__ bias,
    __half* __restrict__ out, int N) {
  __shared__ uint4 lds[4096];  // 64 KB
  int tid = threadIdx.x;
  int wave = tid >> 6, lane = tid & 63;
  int row0 = blockIdx.x * 128;

#pragma unroll
  for (int i = 0; i < 16; i++) lds[i * 256 + tid] = gWsw[i * 256 + tid];
  __syncthreads();

  int mrow = row0 + wave * 32 + (lane & 31);
  int koff = (lane >> 5) * 8;
  bool valid = mrow < N;
  const __half* mrp = mh + (size_t)mrow * D + koff;
  const __half* hrp = hsrc + (size_t)mrow * D + koff;

  floatx16 acc[4];
#pragma unroll
  for (int t = 0; t < 4; t++)
#pragma unroll
    for (int i = 0; i < 16; i++) acc[t][i] = 0.f;

  uint4 areg[8];
#pragma unroll
  for (int k0 = 0; k0 < 8; k0++) {
    areg[k0] = valid ? *(const uint4*)(mrp + k0 * 16) : make_uint4(0u, 0u, 0u, 0u);
  }
#pragma unroll
  for (int k0 = 0; k0 < 8; k0++) {
    half8 af = *(half8*)&areg[k0];
#pragma unroll
    for (int t = 0; t < 4; t++) {
      half8 bf = *(half8*)&lds[(t * 16 + k0) * 64 + lane];
      acc[t] = __builtin_amdgcn_mfma_f32_32x32x16_f16(af, bf, acc[t], 0, 0, 0);
    }
  }
#pragma unroll
  for (int k0 = 0; k0 < 8; k0++) {
    areg[k0] = valid ? *(const uint4*)(hrp + k0 * 16) : make_uint4(0u, 0u, 0u, 0u);
  }
#pragma unroll
  for (int k0 = 8; k0 < 16; k0++) {
    half8 af = *(half8*)&areg[k0 - 8];
#pragma unroll
    for (int t = 0; t < 4; t++) {
      half8 bf = *(half8*)&lds[(t * 16 + k0) * 64 + lane];
      acc[t] = __builtin_amdgcn_mfma_f32_32x32x16_f16(af, bf, acc[t], 0, 0, 0);
    }
  }

  __syncthreads();
  __half* Os = (__half*)lds;
  int col = lane & 31;
  int rsub = 4 * (lane >> 5);
#pragma unroll
  for (int t = 0; t < 4; t++) {
    float bv = bias[t * 32 + col];
#pragma unroll
    for (int r = 0; r < 16; r++) {
      int row = (r & 3) + 8 * (r >> 2) + rsub;
      float v = fmaxf(acc[t][r] + bv, 0.f);
      Os[(size_t)(wave * 32 + row) * OS_PITCH + t * 32 + col] = __float2half_rn(v);
    }
  }
  __syncthreads();
#pragma unroll
  for (int i = 0; i < 8; i++) {
    int idx = i * 256 + tid;
    int row = idx >> 4;
    int c16 = idx & 15;
    int grow = row0 + row;
    if (grow < N) {
      uint4 v = *(uint4*)(Os + (size_t)row * OS_PITCH + c16 * 8);
      *(uint4*)(out + (size_t)grow * D + c16 * 8) = v;
    }
  }
}

// ---------------- pair dot: 16 lanes/pair, 4 pairs/quarter unrolled ----------------
__global__ void pairdot_kernel(const __half* __restrict__ h, const int2* __restrict__ pairs,
                               float* __restrict__ out, int P) {
  int wid = (int)((blockIdx.x * (unsigned)blockDim.x + threadIdx.x) >> 6);
  int lane = threadIdx.x & 63;
  int q = lane >> 4;     // quarter 0..3
  int sub = lane & 15;   // 16 lanes cover one 256B row as uint4
  int base = wid * 16;

  int p[4];
  int2 pr[4];
#pragma unroll
  for (int j = 0; j < 4; j++) {
    p[j] = base + j * 4 + q;
    pr[j] = (p[j] < P) ? pairs[p[j]] : make_int2(0, 0);
  }
  uint4 ur[4], vr[4];
#pragma unroll
  for (int j = 0; j < 4; j++) {
    ur[j] = *(const uint4*)(h + (size_t)pr[j].x * D + sub * 8);
    vr[j] = *(const uint4*)(h + (size_t)pr[j].y * D + sub * 8);
  }
#pragma unroll
  for (int j = 0; j < 4; j++) {
    float2 a0 = h2f(ur[j].x), a1 = h2f(ur[j].y), a2 = h2f(ur[j].z), a3 = h2f(ur[j].w);
    float2 b0 = h2f(vr[j].x), b1 = h2f(vr[j].y), b2 = h2f(vr[j].z), b3 = h2f(vr[j].w);
    float s = a0.x * b0.x + a0.y * b0.y + a1.x * b1.x + a1.y * b1.y +
              a2.x * b2.x + a2.y * b2.y + a3.x * b3.x + a3.y * b3.y;
#pragma unroll
    for (int off = 1; off <= 8; off <<= 1) s += __shfl_xor(s, off);
    if (sub == 0 && p[j] < P) out[p[j]] = s;
  }
}

// ---------------- launcher ----------------
extern "C" void kernel_launch(void* const* d_in, const int* in_sizes, int n_in,
                              void* d_out, int out_size, void* d_ws, size_t ws_size,
                              hipStream_t stream) {
  const int*   x     = (const int*)d_in[0];
  const int*   eidx  = (const int*)d_in[1];
  const int*   pairs = (const int*)d_in[2];
  const float* emb   = (const float*)d_in[3];
  const float* Wl0   = (const float*)d_in[4];
  const float* bl0   = (const float*)d_in[5];
  const float* Wr0   = (const float*)d_in[6];
  const float* Wl1   = (const float*)d_in[7];
  const float* bl1   = (const float*)d_in[8];
  const float* Wr1   = (const float*)d_in[9];

  const int N = in_sizes[0];
  const int E = in_sizes[1] / 2;
  const int P = in_sizes[2] / 2;
  const int* src = eidx;
  const int* dst = eidx + E;

  char* ws = (char*)d_ws;
  size_t off = 0;
  __half* hx  = (__half*)(ws + off); off += (size_t)N * D * sizeof(__half);
  __half* mh  = (__half*)(ws + off); off += (size_t)N * D * sizeof(__half);
  int* rowptr = (int*)(ws + off);    off += ((size_t)N + 64) * sizeof(int);
  int* cnt    = (int*)(ws + off);    off += ((size_t)N + 64) * sizeof(int);
  int* cursor = (int*)(ws + off);    off += ((size_t)N + 64) * sizeof(int);
  int* bsums  = (int*)(ws + off);    off += 4096;
  uint4* gW0  = (uint4*)(ws + off);  off += 65536;
  uint4* gW1  = (uint4*)(ws + off);  off += 65536;
  int* csr    = (int*)(ws + off);    off += (size_t)E * sizeof(int);
  (void)ws_size; (void)n_in; (void)out_size;

  hipMemsetAsync(cnt, 0, (size_t)N * sizeof(int), stream);
  hipMemsetAsync(cursor, 0, (size_t)N * sizeof(int), stream);

  int nbE = (E + 255) / 256;
  int nbS = (N + SCAN_CHUNK - 1) / SCAN_CHUNK;
  hist_kernel<<<nbE, 256, 0, stream>>>(dst, cnt, E);
  scan1_kernel<<<nbS, SCAN_TPB, 0, stream>>>(cnt, rowptr, bsums, N);
  scan2_kernel<<<1, 64, 0, stream>>>(bsums, nbS);
  scan3_kernel<<<nbS, SCAN_TPB, 0, stream>>>(rowptr, bsums, N, E);
  scatter_kernel<<<nbE, 256, 0, stream>>>(src, dst, rowptr, cursor, csr, E);

  packW_kernel<<<16, 256, 0, stream>>>(Wl0, Wr0, gW0);
  packW_kernel<<<16, 256, 0, stream>>>(Wl1, Wr1, gW1);

  int nbA = (N + 3) / 4;
  int nbG = (N + 127) / 128;

  cast_kernel<<<nbA, 256, 0, stream>>>(emb, x, hx, N);

  agg_kernel<<<nbA, 256, 0, stream>>>(hx, rowptr, csr, mh, N);
  mfma_gemm_kernel<<<nbG, 256, 0, stream>>>(mh, hx, gW0, bl0, hx, N);
  agg_kernel<<<nbA, 256, 0, stream>>>(hx, rowptr, csr, mh, N);
  mfma_gemm_kernel<<<nbG, 256, 0, stream>>>(mh, hx, gW1, bl1, hx, N);

  // 16 pairs per wave, 4 waves per block -> 64 pairs/block
  int nbP = (P + 63) / 64;
  pairdot_kernel<<<nbP, 256, 0, stream>>>(hx, (const int2*)pairs, (float*)d_out, P);
}

// Round 5
// 501.842 us; speedup vs baseline: 1.9399x; 1.0224x over previous
//
#include <hip/hip_runtime.h>
#include <hip/hip_fp16.h>

#define D 128

typedef _Float16 half8 __attribute__((ext_vector_type(8)));
typedef float floatx16 __attribute__((ext_vector_type(16)));

__device__ inline float2 h2f(unsigned int u) {
  __half2 h = *(__half2*)&u;
  return __half22float2(h);
}

// ---------------- CSR build ----------------
__global__ void hist_kernel(const int* __restrict__ dst, int* __restrict__ cnt, int E) {
  int e = blockIdx.x * blockDim.x + threadIdx.x;
  if (e < E) atomicAdd(&cnt[dst[e]], 1);
}

#define SCAN_TPB 256
#define SCAN_EPT 8
#define SCAN_CHUNK (SCAN_TPB * SCAN_EPT)  // 2048

__global__ void scan1_kernel(const int* __restrict__ cnt, int* __restrict__ rowptr,
                             int* __restrict__ bsums, int N) {
  __shared__ int lds[SCAN_TPB];
  int tid = threadIdx.x;
  int base = blockIdx.x * SCAN_CHUNK + tid * SCAN_EPT;
  int v[SCAN_EPT];
  int tsum = 0;
#pragma unroll
  for (int j = 0; j < SCAN_EPT; j++) {
    int i = base + j;
    v[j] = (i < N) ? cnt[i] : 0;
    tsum += v[j];
  }
  lds[tid] = tsum;
  __syncthreads();
  for (int off = 1; off < SCAN_TPB; off <<= 1) {
    int t = (tid >= off) ? lds[tid - off] : 0;
    __syncthreads();
    lds[tid] += t;
    __syncthreads();
  }
  int excl = lds[tid] - tsum;
  if (tid == SCAN_TPB - 1) bsums[blockIdx.x] = lds[tid];
  int run = excl;
#pragma unroll
  for (int j = 0; j < SCAN_EPT; j++) {
    int i = base + j;
    if (i < N) rowptr[i] = run;
    run += v[j];
  }
}

__global__ void scan2_kernel(int* bsums, int nb) {
  if (threadIdx.x == 0 && blockIdx.x == 0) {
    int run = 0;
    for (int i = 0; i < nb; i++) { int t = bsums[i]; bsums[i] = run; run += t; }
  }
}

__global__ void scan3_kernel(int* __restrict__ rowptr, const int* __restrict__ bsums,
                             int N, int E) {
  int tid = threadIdx.x;
  int base = blockIdx.x * SCAN_CHUNK + tid * SCAN_EPT;
  int off = bsums[blockIdx.x];
#pragma unroll
  for (int j = 0; j < SCAN_EPT; j++) {
    int i = base + j;
    if (i < N) rowptr[i] += off;
  }
  if (blockIdx.x == 0 && tid == 0) rowptr[N] = E;
}

// XCD-partitioned scatter: block b covers edge chunk (b>>3) for dst segment (b&7).
// Consecutive blocks land on different XCDs (round-robin heuristic), so each XCD's
// L2 owns one ~800KB csr slice -> full cache lines, no partial-line writebacks.
#define SC_EPT 8
__global__ void scatter_kernel(const int* __restrict__ src, const int* __restrict__ dst,
                               const int* __restrict__ rowptr, int* __restrict__ cursor,
                               int* __restrict__ csr_src, int E, int N) {
  int seg = blockIdx.x & 7;
  int chunk = blockIdx.x >> 3;
  int lo = (int)((long long)seg * N / 8);
  int hi = (int)((long long)(seg + 1) * N / 8);
  int base = chunk * (256 * SC_EPT) + threadIdx.x;
#pragma unroll
  for (int j = 0; j < SC_EPT; j++) {
    int e = base + j * 256;
    if (e < E) {
      int d = dst[e];
      if (d >= lo && d < hi) {
        int pos = rowptr[d] + atomicAdd(&cursor[d], 1);
        csr_src[pos] = src[e];
      }
    }
  }
}

// ---------------- hx = fp16(emb[x]) ----------------
__global__ void cast_kernel(const float* __restrict__ emb, const int* __restrict__ x,
                            __half* __restrict__ hx, int N) {
  int w = (int)((blockIdx.x * (unsigned)blockDim.x + threadIdx.x) >> 6);
  int lane = threadIdx.x & 63;
  if (w >= N) return;
  int xi = x[w];
  float2 v = ((const float2*)(emb + (size_t)xi * D))[lane];
  ((__half2*)(hx + (size_t)w * D))[lane] = __floats2half2_rn(v.x, v.y);
}

// ---------------- mean aggregation (one wave per node, 8-deep gather MLP) --------
__global__ void agg_kernel(const __half* __restrict__ hh, const int* __restrict__ rowptr,
                           const int* __restrict__ csr, __half* __restrict__ mh, int N) {
  int node = (int)((blockIdx.x * (unsigned)blockDim.x + threadIdx.x) >> 6);
  int lane = threadIdx.x & 63;
  if (node >= N) return;
  int beg = rowptr[node], end = rowptr[node + 1];
  const unsigned int* h1 = (const unsigned int*)hh;
  float sx = 0.f, sy = 0.f;
  int e = beg;
  for (; e + 8 <= end; e += 8) {
    int s[8];
#pragma unroll
    for (int j = 0; j < 8; j++) s[j] = csr[e + j];
    unsigned int r[8];
#pragma unroll
    for (int j = 0; j < 8; j++) r[j] = h1[(size_t)s[j] * 64 + lane];
#pragma unroll
    for (int j = 0; j < 8; j++) {
      float2 f = h2f(r[j]);
      sx += f.x; sy += f.y;
    }
  }
  for (; e + 2 <= end; e += 2) {
    int s0 = csr[e], s1 = csr[e + 1];
    unsigned int a = h1[(size_t)s0 * 64 + lane];
    unsigned int b = h1[(size_t)s1 * 64 + lane];
    float2 fa = h2f(a), fb = h2f(b);
    sx += fa.x + fb.x; sy += fa.y + fb.y;
  }
  if (e < end) {
    float2 fa = h2f(h1[(size_t)csr[e] * 64 + lane]);
    sx += fa.x; sy += fa.y;
  }
  float inv = 1.0f / fmaxf((float)(end - beg), 1.0f);
  ((__half2*)mh)[(size_t)node * 64 + lane] = __floats2half2_rn(sx * inv, sy * inv);
}

// ---------------- pack W into B-fragment order ----------------
__global__ void packW_kernel(const float* __restrict__ Wl, const float* __restrict__ Wr,
                             uint4* __restrict__ gWsw) {
  int g = blockIdx.x * blockDim.x + threadIdx.x;
  if (g >= 4096) return;
  int lane = g & 63;
  int k0 = (g >> 6) & 15;
  int t = g >> 10;
  int n = t * 32 + (lane & 31);
  int kk = k0 * 16 + (lane >> 5) * 8;
  const float* srcp = (kk < D) ? (Wl + (size_t)n * D + kk) : (Wr + (size_t)n * D + (kk - D));
  float4 f0 = *(const float4*)(srcp);
  float4 f1 = *(const float4*)(srcp + 4);
  __half h[8];
  h[0] = __float2half_rn(f0.x); h[1] = __float2half_rn(f0.y);
  h[2] = __float2half_rn(f0.z); h[3] = __float2half_rn(f0.w);
  h[4] = __float2half_rn(f1.x); h[5] = __float2half_rn(f1.y);
  h[6] = __float2half_rn(f1.z); h[7] = __float2half_rn(f1.w);
  gWsw[g] = *(uint4*)h;
}

// ---------------- MFMA GEMM: out = fp16(relu([mean|h] @ B + bias)) ----------------
#define OS_PITCH 136

__global__ __launch_bounds__(256) void mfma_gemm_kernel(
    const __half* __restrict__ mh, const __half* __restrict__ hsrc,
    const uint4* __restrict__ gWsw, const float* __restrict__ bias,
    __half* __restrict__ out, int N) {
  __shared__ uint4 lds[4096];  // 64 KB
  int tid = threadIdx.x;
  int wave = tid >> 6, lane = tid & 63;
  int row0 = blockIdx.x * 128;

#pragma unroll
  for (int i = 0; i < 16; i++) lds[i * 256 + tid] = gWsw[i * 256 + tid];
  __syncthreads();

  int mrow = row0 + wave * 32 + (lane & 31);
  int koff = (lane >> 5) * 8;
  bool valid = mrow < N;
  const __half* mrp = mh + (size_t)mrow * D + koff;
  const __half* hrp = hsrc + (size_t)mrow * D + koff;

  floatx16 acc[4];
#pragma unroll
  for (int t = 0; t < 4; t++)
#pragma unroll
    for (int i = 0; i < 16; i++) acc[t][i] = 0.f;

  uint4 areg[8];
#pragma unroll
  for (int k0 = 0; k0 < 8; k0++) {
    areg[k0] = valid ? *(const uint4*)(mrp + k0 * 16) : make_uint4(0u, 0u, 0u, 0u);
  }
#pragma unroll
  for (int k0 = 0; k0 < 8; k0++) {
    half8 af = *(half8*)&areg[k0];
#pragma unroll
    for (int t = 0; t < 4; t++) {
      half8 bf = *(half8*)&lds[(t * 16 + k0) * 64 + lane];
      acc[t] = __builtin_amdgcn_mfma_f32_32x32x16_f16(af, bf, acc[t], 0, 0, 0);
    }
  }
#pragma unroll
  for (int k0 = 0; k0 < 8; k0++) {
    areg[k0] = valid ? *(const uint4*)(hrp + k0 * 16) : make_uint4(0u, 0u, 0u, 0u);
  }
#pragma unroll
  for (int k0 = 8; k0 < 16; k0++) {
    half8 af = *(half8*)&areg[k0 - 8];
#pragma unroll
    for (int t = 0; t < 4; t++) {
      half8 bf = *(half8*)&lds[(t * 16 + k0) * 64 + lane];
      acc[t] = __builtin_amdgcn_mfma_f32_32x32x16_f16(af, bf, acc[t], 0, 0, 0);
    }
  }

  __syncthreads();
  __half* Os = (__half*)lds;
  int col = lane & 31;
  int rsub = 4 * (lane >> 5);
#pragma unroll
  for (int t = 0; t < 4; t++) {
    float bv = bias[t * 32 + col];
#pragma unroll
    for (int r = 0; r < 16; r++) {
      int row = (r & 3) + 8 * (r >> 2) + rsub;
      float v = fmaxf(acc[t][r] + bv, 0.f);
      Os[(size_t)(wave * 32 + row) * OS_PITCH + t * 32 + col] = __float2half_rn(v);
    }
  }
  __syncthreads();
#pragma unroll
  for (int i = 0; i < 8; i++) {
    int idx = i * 256 + tid;
    int row = idx >> 4;
    int c16 = idx & 15;
    int grow = row0 + row;
    if (grow < N) {
      uint4 v = *(uint4*)(Os + (size_t)row * OS_PITCH + c16 * 8);
      *(uint4*)(out + (size_t)grow * D + c16 * 8) = v;
    }
  }
}

// ---------------- pair dot: 16 lanes/pair, 4 pairs/quarter unrolled ----------------
__global__ void pairdot_kernel(const __half* __restrict__ h, const int2* __restrict__ pairs,
                               float* __restrict__ out, int P) {
  int wid = (int)((blockIdx.x * (unsigned)blockDim.x + threadIdx.x) >> 6);
  int lane = threadIdx.x & 63;
  int q = lane >> 4;
  int sub = lane & 15;
  int base = wid * 16;

  int p[4];
  int2 pr[4];
#pragma unroll
  for (int j = 0; j < 4; j++) {
    p[j] = base + j * 4 + q;
    pr[j] = (p[j] < P) ? pairs[p[j]] : make_int2(0, 0);
  }
  uint4 ur[4], vr[4];
#pragma unroll
  for (int j = 0; j < 4; j++) {
    ur[j] = *(const uint4*)(h + (size_t)pr[j].x * D + sub * 8);
    vr[j] = *(const uint4*)(h + (size_t)pr[j].y * D + sub * 8);
  }
#pragma unroll
  for (int j = 0; j < 4; j++) {
    float2 a0 = h2f(ur[j].x), a1 = h2f(ur[j].y), a2 = h2f(ur[j].z), a3 = h2f(ur[j].w);
    float2 b0 = h2f(vr[j].x), b1 = h2f(vr[j].y), b2 = h2f(vr[j].z), b3 = h2f(vr[j].w);
    float s = a0.x * b0.x + a0.y * b0.y + a1.x * b1.x + a1.y * b1.y +
              a2.x * b2.x + a2.y * b2.y + a3.x * b3.x + a3.y * b3.y;
#pragma unroll
    for (int off = 1; off <= 8; off <<= 1) s += __shfl_xor(s, off);
    if (sub == 0 && p[j] < P) out[p[j]] = s;
  }
}

// ---------------- launcher ----------------
extern "C" void kernel_launch(void* const* d_in, const int* in_sizes, int n_in,
                              void* d_out, int out_size, void* d_ws, size_t ws_size,
                              hipStream_t stream) {
  const int*   x     = (const int*)d_in[0];
  const int*   eidx  = (const int*)d_in[1];
  const int*   pairs = (const int*)d_in[2];
  const float* emb   = (const float*)d_in[3];
  const float* Wl0   = (const float*)d_in[4];
  const float* bl0   = (const float*)d_in[5];
  const float* Wr0   = (const float*)d_in[6];
  const float* Wl1   = (const float*)d_in[7];
  const float* bl1   = (const float*)d_in[8];
  const float* Wr1   = (const float*)d_in[9];

  const int N = in_sizes[0];
  const int E = in_sizes[1] / 2;
  const int P = in_sizes[2] / 2;
  const int* src = eidx;
  const int* dst = eidx + E;

  char* ws = (char*)d_ws;
  size_t off = 0;
  __half* hx  = (__half*)(ws + off); off += (size_t)N * D * sizeof(__half);
  __half* mh  = (__half*)(ws + off); off += (size_t)N * D * sizeof(__half);
  int* rowptr = (int*)(ws + off);    off += ((size_t)N + 64) * sizeof(int);
  int* cnt    = (int*)(ws + off);    off += ((size_t)N + 64) * sizeof(int);
  int* cursor = (int*)(ws + off);    off += ((size_t)N + 64) * sizeof(int);
  int* bsums  = (int*)(ws + off);    off += 4096;
  uint4* gW0  = (uint4*)(ws + off);  off += 65536;
  uint4* gW1  = (uint4*)(ws + off);  off += 65536;
  int* csr    = (int*)(ws + off);    off += (size_t)E * sizeof(int);
  (void)ws_size; (void)n_in; (void)out_size;

  hipMemsetAsync(cnt, 0, (size_t)N * sizeof(int), stream);
  hipMemsetAsync(cursor, 0, (size_t)N * sizeof(int), stream);

  int nbE = (E + 255) / 256;
  int nbS = (N + SCAN_CHUNK - 1) / SCAN_CHUNK;
  hist_kernel<<<nbE, 256, 0, stream>>>(dst, cnt, E);
  scan1_kernel<<<nbS, SCAN_TPB, 0, stream>>>(cnt, rowptr, bsums, N);
  scan2_kernel<<<1, 64, 0, stream>>>(bsums, nbS);
  scan3_kernel<<<nbS, SCAN_TPB, 0, stream>>>(rowptr, bsums, N, E);

  int nchunk = (E + 256 * SC_EPT - 1) / (256 * SC_EPT);
  scatter_kernel<<<nchunk * 8, 256, 0, stream>>>(src, dst, rowptr, cursor, csr, E, N);

  packW_kernel<<<16, 256, 0, stream>>>(Wl0, Wr0, gW0);
  packW_kernel<<<16, 256, 0, stream>>>(Wl1, Wr1, gW1);

  int nbA = (N + 3) / 4;
  int nbG = (N + 127) / 128;

  cast_kernel<<<nbA, 256, 0, stream>>>(emb, x, hx, N);

  agg_kernel<<<nbA, 256, 0, stream>>>(hx, rowptr, csr, mh, N);
  mfma_gemm_kernel<<<nbG, 256, 0, stream>>>(mh, hx, gW0, bl0, hx, N);
  agg_kernel<<<nbA, 256, 0, stream>>>(hx, rowptr, csr, mh, N);
  mfma_gemm_kernel<<<nbG, 256, 0, stream>>>(mh, hx, gW1, bl1, hx, N);

  int nbP = (P + 63) / 64;
  pairdot_kernel<<<nbP, 256, 0, stream>>>(hx, (const int2*)pairs, (float*)d_out, P);
}